// Round 11
// baseline (206.210 us; speedup 1.0000x reference)
//
#include <hip/hip_runtime.h>
#include <hip/hip_bf16.h>

typedef __hip_bfloat16 bf16;
typedef __bf16 b16x8 __attribute__((ext_vector_type(8)));
typedef float f32x4 __attribute__((ext_vector_type(4)));
typedef float f32x2 __attribute__((ext_vector_type(2)));

#define HWs   12800   // 80*160
#define NPIX  25600   // 2*80*160
#define IMG_H 80
#define IMG_W 160

// bf16 weight-cache element offsets inside wbuf
#define OFF_VCB  0        // 128x128
#define OFF_VGB  16384    // 128x128
#define OFF_MATB 32768    // 162x128  (wc|wg|kpc|kpg concatenated; reads up to row 175 spill into OUTB, stores guarded)
#define OFF_OUTB 53504    // 128x256
#define NW_BF16  86272

// fp8 e4m3 (OCP, gfx950-native) encode one float -> byte
static __device__ inline unsigned char enc_fp8(float v)
{
    return (unsigned char)(__builtin_amdgcn_cvt_pk_fp8_f32(v, v, 0, false) & 0xFF);
}

// ---------------- k_prep: f32 -> bf16 weight cache + concatenated bias ----------------
__global__ __launch_bounds__(256) void k_prep(
    const float* __restrict__ vc_w, const float* __restrict__ vg_w,
    const float* __restrict__ wc_w, const float* __restrict__ wg_w,
    const float* __restrict__ kpc_w, const float* __restrict__ kpg_w,
    const float* __restrict__ out_w,
    const float* __restrict__ wc_b, const float* __restrict__ wg_b,
    const float* __restrict__ kpc_b, const float* __restrict__ kpg_b,
    bf16* __restrict__ wbuf, float* __restrict__ bias176)
{
    int i = blockIdx.x * 256 + threadIdx.x;
    if (i < 16384) {
        wbuf[i] = __float2bfloat16(vc_w[i]);
    } else if (i < 32768) {
        wbuf[i] = __float2bfloat16(vg_w[i - 16384]);
    } else if (i < 53504) {
        int j = i - 32768; int row = j >> 7; int c = j & 127;
        float v;
        if (row < 72)       v = wc_w[row * 128 + c];
        else if (row < 144) v = wg_w[(row - 72) * 128 + c];
        else if (row < 153) v = kpc_w[(row - 144) * 128 + c];
        else                v = kpg_w[(row - 153) * 128 + c];
        wbuf[i] = __float2bfloat16(v);
    } else if (i < NW_BF16) {
        wbuf[i] = __float2bfloat16(out_w[i - 53504]);
    } else if (i < NW_BF16 + 176) {
        int j = i - NW_BF16;
        float v = 0.f;
        if (j < 72)       v = wc_b[j];
        else if (j < 144) v = wg_b[j - 72];
        else if (j < 153) v = kpc_b[j - 144];
        else if (j < 162) v = kpg_b[j - 153];
        bias176[j] = v;
    }
}

// ---------------- Stage 1: fused LN + GEMMs, float4 LN loads + weight prefetch ----------------
// blocks [0,800): context+vc -> ctx8 (fp8) ; [800,1600): geometric+vg -> geo8 ;
// [1600,2400): match branch -> softmax wts, coords, kp_out.
__global__ __launch_bounds__(256) void k_stage1(
    const float* __restrict__ match, const float* __restrict__ context, const float* __restrict__ geometric,
    const float* __restrict__ ln_g, const float* __restrict__ ln_b,
    const float* __restrict__ lnc_g, const float* __restrict__ lnc_b,
    const float* __restrict__ lng_g, const float* __restrict__ lng_b,
    const float* __restrict__ vc_b, const float* __restrict__ vg_b,
    const bf16* __restrict__ wbuf, const float* __restrict__ bias176,
    const float* __restrict__ anc_c, const float* __restrict__ anc_g,
    unsigned char* __restrict__ ctx8, unsigned char* __restrict__ geo8,
    bf16* __restrict__ wts_g, float* __restrict__ coords_g,
    float* __restrict__ kp_out)
{
    // ubuf: f32 staging tile (128ch x pitch36) during LN; reused for logits/offs after sync2
    __shared__ __align__(16) char ubuf[128 * 36 * 4];       // 18432 B
    __shared__ __align__(16) bf16 tile_s[32 * 136];         //  8704 B
    __shared__ float red1[8][32];
    __shared__ float red2[8][32];
    float* smemf  = (float*)ubuf;
    bf16* logit_s = (bf16*)ubuf;                 // 32*144*2 = 9216 B
    float* offs_s = (float*)(ubuf + 9216);       // 32*18*4  = 2304 B

    int bx = blockIdx.x;
    int seg = bx / 800;                  // 0 ctx, 1 geo, 2 match
    int tile = bx - seg * 800;
    int t = threadIdx.x;
    int pixbase = tile * 32;

    const float* X  = (seg == 0) ? context : (seg == 1) ? geometric : match;
    const float* gg = (seg == 0) ? lnc_g   : (seg == 1) ? lng_g     : ln_g;
    const float* bb = (seg == 0) ? lnc_b   : (seg == 1) ? lng_b     : ln_b;

    // ---- phase A: vectorized float4 LN loads (issued first) ----
    int b = pixbase >= HWs;
    int hw0 = pixbase - b * HWs;
    const float* Xb = X + ((size_t)b * 128) * HWs + hw0;
    float4 va[4];
#pragma unroll
    for (int i = 0; i < 4; i++) {
        int id = t + 256 * i;            // 0..1023 ; c = id>>3, j = id&7
        va[i] = *(const float4*)(Xb + (size_t)(id >> 3) * HWs + (id & 7) * 4);
    }

    // ---- prefetch this wave's B-fragments (independent of LN) ----
    int wv = t >> 6;
    int lane = t & 63;
    int s = wv >> 1;                     // subtile of 16 pixels
    int h = wv & 1;                      // output-tile parity
    int lrow = lane & 15;
    int lq = lane >> 4;
    const bf16* Wb = (seg == 0) ? wbuf + OFF_VCB
                   : (seg == 1) ? wbuf + OFF_VGB
                                : wbuf + OFF_MATB;
    b16x8 wf[4][4];
    float bpre[4];
#pragma unroll
    for (int i = 0; i < 4; i++) {
        int o = (h + 2 * i) * 16 + lrow;            // match: o <= 111 < 162, safe
        const bf16* wr = Wb + (size_t)o * 128;
#pragma unroll
        for (int kk = 0; kk < 4; kk++)
            wf[i][kk] = *(const b16x8*)(wr + (kk * 4 + lq) * 8);
        bpre[i] = (seg == 0) ? vc_b[o] : (seg == 1) ? vg_b[o] : bias176[o];
    }

    // ---- stage to LDS f32 tile (pitch 36) ----
#pragma unroll
    for (int i = 0; i < 4; i++) {
        int id = t + 256 * i;
        *(float4*)(smemf + (id >> 3) * 36 + (id & 7) * 4) = va[i];
    }
    __syncthreads();

    // ---- LN reduce + normalized bf16 tile ----
    int p = t & 31;
    int cq = t >> 5;
    float xv[16];
    {
        float s1 = 0.f, s2 = 0.f;
#pragma unroll
        for (int j = 0; j < 16; j++) {
            float v = smemf[(cq * 16 + j) * 36 + p];
            xv[j] = v; s1 += v; s2 += v * v;
        }
        red1[cq][p] = s1; red2[cq][p] = s2;
        __syncthreads();
        float S1 = 0.f, S2 = 0.f;
#pragma unroll
        for (int q = 0; q < 8; q++) { S1 += red1[q][p]; S2 += red2[q][p]; }
        float mean = S1 * (1.f / 128.f);
        float var  = fmaxf(S2 * (1.f / 128.f) - mean * mean, 0.f);
        float rstd = rsqrtf(var + 1e-5f);
#pragma unroll
        for (int j = 0; j < 16; j++) {
            int c = cq * 16 + j;
            float y = (xv[j] - mean) * rstd * gg[c] + bb[c];
            tile_s[p * 136 + c] = __float2bfloat16(y);
        }
        __syncthreads();   // tile_s ready; smemf reads done -> ubuf reusable as logit_s
    }

    // ---- A fragments ----
    const b16x8* arow = (const b16x8*)(tile_s + (s * 16 + lrow) * 136);
    b16x8 af[4];
#pragma unroll
    for (int kk = 0; kk < 4; kk++) af[kk] = arow[kk * 4 + lq];

    if (seg < 2) {
        unsigned char* val = (seg == 0) ? ctx8 : geo8;
#pragma unroll
        for (int i = 0; i < 4; i++) {
            int o = (h + 2 * i) * 16 + lrow;
            f32x4 acc = {0.f, 0.f, 0.f, 0.f};
#pragma unroll
            for (int kk = 0; kk < 4; kk++)
                acc = __builtin_amdgcn_mfma_f32_16x16x32_bf16(af[kk], wf[i][kk], acc, 0, 0, 0);
#pragma unroll
            for (int r = 0; r < 4; r++) {
                int pix = pixbase + s * 16 + lq * 4 + r;   // C/D: row = lq*4+r, col = lrow
                val[(size_t)pix * 128 + o] = enc_fp8(acc[r] + bpre[i]);
            }
        }
        return;
    }

    // ---- seg == 2: match branch ----
#pragma unroll
    for (int i = 0; i < 4; i++) {
        int o = (h + 2 * i) * 16 + lrow;
        f32x4 acc = {0.f, 0.f, 0.f, 0.f};
#pragma unroll
        for (int kk = 0; kk < 4; kk++)
            acc = __builtin_amdgcn_mfma_f32_16x16x32_bf16(af[kk], wf[i][kk], acc, 0, 0, 0);
#pragma unroll
        for (int r = 0; r < 4; r++) {
            int row = s * 16 + lq * 4 + r;
            logit_s[row * 144 + o] = __float2bfloat16(acc[r] + bpre[i]);
        }
    }
    for (int ot = h + 8; ot < 11; ot += 2) {        // h=0: 8,10 ; h=1: 9
        int o = ot * 16 + lrow;                     // up to 175; reads padded, stores guarded
        const bf16* wr = Wb + (size_t)o * 128;
        f32x4 acc = {0.f, 0.f, 0.f, 0.f};
#pragma unroll
        for (int kk = 0; kk < 4; kk++)
            acc = __builtin_amdgcn_mfma_f32_16x16x32_bf16(af[kk], *(const b16x8*)(wr + (kk * 4 + lq) * 8), acc, 0, 0, 0);
        float bias = bias176[o];
#pragma unroll
        for (int r = 0; r < 4; r++) {
            int row = s * 16 + lq * 4 + r;
            float v = acc[r] + bias;
            if (o < 144)       logit_s[row * 144 + o] = __float2bfloat16(v);
            else if (o < 162)  offs_s[row * 18 + (o - 144)] = v;
        }
    }
    __syncthreads();

    // softmax over P per (pixel, branch, group): 512 tasks
#pragma unroll
    for (int i = 0; i < 2; i++) {
        int task = t + 256 * i;
        int lp = task >> 4;
        int sub = task & 15;
        int br = sub >> 3;
        int g = sub & 7;
        const bf16* basel = logit_s + lp * 144 + br * 72 + g;   // channel c = p*8+g
        float v[9];
        float m = -1e30f;
#pragma unroll
        for (int pp = 0; pp < 9; pp++) { v[pp] = __bfloat162float(basel[pp * 8]); m = fmaxf(m, v[pp]); }
        float ssum = 0.f;
#pragma unroll
        for (int pp = 0; pp < 9; pp++) { v[pp] = __expf(v[pp] - m); ssum += v[pp]; }
        float inv = 1.f / ssum;
        int pix = pixbase + lp;
        bf16* wbp = wts_g + ((size_t)pix * 2 + br) * 72 + g * 9;
#pragma unroll
        for (int pp = 0; pp < 9; pp++) wbp[pp] = __float2bfloat16(v[pp] * inv);
    }

    // keypoints + sample coords: 576 tasks (kp_out f32 = ref output dtype)
    for (int i = 0; i < 3; i++) {
        int task = t + 256 * i;
        if (task < 576) {
            int lp = task / 18;
            int sub = task - lp * 18;
            int br = sub / 9;
            int pp = sub - br * 9;
            int pix = pixbase + lp;
            float off = offs_s[lp * 18 + br * 9 + pp];
            const float* anc = br ? anc_g : anc_c;
            float ax = anc[(size_t)pix * 18 + pp * 2];
            float ay = anc[(size_t)pix * 18 + pp * 2 + 1];
            float kx = ax + off;
            float* kpo = kp_out + (size_t)br * (NPIX * 18) + (size_t)pix * 18 + pp * 2;
            kpo[0] = kx;
            kpo[1] = ay;
            float* cbp = coords_g + ((size_t)pix * 2 + br) * 18 + pp * 2;
            cbp[0] = kx * 160.f - 0.5f;
            cbp[1] = ay * 80.f - 0.5f;
        }
    }
}

// ---------------- bilinear gather (fp8) + aggregate, XCD-partitioned, packed math ----------------
// Quarter-wave (16 lanes) per (pixel,branch) task; lane owns 8 channels (8 B fp8).
// blockIdx&7 ~ XCD (round-robin dispatch): XCDs 0-3 -> ctx, 4-7 -> geo.
__global__ __launch_bounds__(256) void k_agg(
    const unsigned char* __restrict__ ctx8, const unsigned char* __restrict__ geo8,
    const bf16* __restrict__ wts_g, const float* __restrict__ coords_g,
    const float* __restrict__ mask,
    bf16* __restrict__ aggf)
{
    int t = threadIdx.x;
    int wv = t >> 6;
    int lane = t & 63;
    int q = lane >> 4;           // quarter-wave task slot
    int sub = lane & 15;         // channel octet
    int c0 = sub * 8;
    int g = sub >> 1;            // group = c/16

    int bx = blockIdx.x;         // 0..3199
    int xcd = bx & 7;
    int br = xcd >> 2;           // XCDs 0-3 -> ctx, 4-7 -> geo
    int grp = (bx >> 3) * 4 + (xcd & 3);      // 0..1599
    int pix = grp * 16 + wv * 4 + q;          // 0..25599
    int tk = pix * 2 + br;
    int b = pix >= HWs;
    int rowbase = b * HWs;

    const unsigned char* val = br ? geo8 : ctx8;
    const float* cb = coords_g + (size_t)tk * 18;
    const bf16* wb = wts_g + (size_t)tk * 72 + g * 9;

    float wtv[9];
#pragma unroll
    for (int pp = 0; pp < 9; pp++) wtv[pp] = __bfloat162float(wb[pp]);

    f32x2 acc2[4] = {{0.f, 0.f}, {0.f, 0.f}, {0.f, 0.f}, {0.f, 0.f}};
    for (int pp = 0; pp < 9; pp++) {
        float px = cb[pp * 2];
        float py = cb[pp * 2 + 1];
        float fx = floorf(px), fy = floorf(py);
        float dx = px - fx, dy = py - fy;
        int x0 = (int)fx, y0 = (int)fy;
        float wt = wtv[pp];
#pragma unroll
        for (int c4 = 0; c4 < 4; c4++) {
            int xi = x0 + (c4 & 1);
            int yi = y0 + (c4 >> 1);
            bool ok = (xi >= 0) & (xi < IMG_W) & (yi >= 0) & (yi < IMG_H);
            int xc = min(max(xi, 0), IMG_W - 1);
            int yc = min(max(yi, 0), IMG_H - 1);
            float wx = (c4 & 1) ? dx : 1.f - dx;
            float wy = (c4 >> 1) ? dy : 1.f - dy;
            float wgt = ok ? wx * wy * wt : 0.f;
            f32x2 w2 = {wgt, wgt};
            uint2 u = *(const uint2*)(val + (size_t)(rowbase + yc * IMG_W + xc) * 128 + c0);
            acc2[0] += w2 * __builtin_amdgcn_cvt_pk_f32_fp8(u.x, false);
            acc2[1] += w2 * __builtin_amdgcn_cvt_pk_f32_fp8(u.x, true);
            acc2[2] += w2 * __builtin_amdgcn_cvt_pk_f32_fp8(u.y, false);
            acc2[3] += w2 * __builtin_amdgcn_cvt_pk_f32_fp8(u.y, true);
        }
    }
    float mv = (br == 0) ? mask[pix] : 1.f;
    b16x8 pk;
#pragma unroll
    for (int j = 0; j < 8; j++) pk[j] = (__bf16)(acc2[j >> 1][j & 1] * mv);
    *(b16x8*)(aggf + (size_t)pix * 256 + br * 128 + c0) = pk;
}

// ---------------- final projection (MFMA, K=256) + transposed f32 store ----------------
__global__ __launch_bounds__(256) void k_out(
    const bf16* __restrict__ aggf,
    const bf16* __restrict__ outb, const float* __restrict__ out_b,
    float* __restrict__ out)
{
    int t = threadIdx.x;
    int pixbase = blockIdx.x * 32;       // 800 blocks
    int wv = t >> 6;
    int lane = t & 63;
    int s = wv >> 1;
    int h = wv & 1;
    int lrow = lane & 15;
    int lq = lane >> 4;
    const b16x8* arow = (const b16x8*)(aggf + (size_t)(pixbase + s * 16 + lrow) * 256);
    b16x8 af[8];
#pragma unroll
    for (int kk = 0; kk < 8; kk++) af[kk] = arow[kk * 4 + lq];
    int b = pixbase >= HWs;
#pragma unroll
    for (int i = 0; i < 4; i++) {
        int o = (h + 2 * i) * 16 + lrow;
        const bf16* wrow = outb + (size_t)o * 256;
        f32x4 acc = {0.f, 0.f, 0.f, 0.f};
#pragma unroll
        for (int kk = 0; kk < 8; kk++)
            acc = __builtin_amdgcn_mfma_f32_16x16x32_bf16(af[kk], *(const b16x8*)(wrow + (kk * 4 + lq) * 8), acc, 0, 0, 0);
        float bias = out_b[o];
#pragma unroll
        for (int r = 0; r < 4; r++) {
            int pix = pixbase + s * 16 + lq * 4 + r;
            int hw = pix - b * HWs;
            out[(size_t)b * (128 * HWs) + (size_t)o * HWs + hw] = acc[r] + bias;
        }
    }
}

extern "C" void kernel_launch(void* const* d_in, const int* in_sizes, int n_in,
                              void* d_out, int out_size, void* d_ws, size_t ws_size,
                              hipStream_t stream)
{
    const float* mask      = (const float*)d_in[0];
    const float* match     = (const float*)d_in[1];
    const float* context   = (const float*)d_in[2];
    const float* geometric = (const float*)d_in[3];
    const float* anc_c     = (const float*)d_in[4];
    const float* anc_g     = (const float*)d_in[5];
    const float* ln_g  = (const float*)d_in[6];
    const float* ln_b  = (const float*)d_in[7];
    const float* lnc_g = (const float*)d_in[8];
    const float* lnc_b = (const float*)d_in[9];
    const float* lng_g = (const float*)d_in[10];
    const float* lng_b = (const float*)d_in[11];
    const float* wc_w  = (const float*)d_in[12];
    const float* wc_b  = (const float*)d_in[13];
    const float* wg_w  = (const float*)d_in[14];
    const float* wg_b  = (const float*)d_in[15];
    const float* vc_w  = (const float*)d_in[16];
    const float* vc_b  = (const float*)d_in[17];
    const float* vg_w  = (const float*)d_in[18];
    const float* vg_b  = (const float*)d_in[19];
    const float* out_w = (const float*)d_in[20];
    const float* out_b = (const float*)d_in[21];
    const float* kpc_w = (const float*)d_in[22];
    const float* kpc_b = (const float*)d_in[23];
    const float* kpg_w = (const float*)d_in[24];
    const float* kpg_b = (const float*)d_in[25];

    // d_ws layout
    char* w = (char*)d_ws;
    unsigned char* ctx8 = (unsigned char*)(w);            //  3,276,800 B (fp8)
    unsigned char* geo8 = (unsigned char*)(w + 3276800);  //  3,276,800 B
    bf16*  wts_g    = (bf16*)(w + 6553600);               //  7,372,800 B
    float* coords_g = (float*)(w + 13926400);             //  3,686,400 B
    bf16*  aggf     = (bf16*)(w + 17612800);              // 13,107,200 B
    bf16*  wbuf     = (bf16*)(w + 30720000);              //    172,544 B
    float* bias176  = (float*)(w + 30892544);             //        704 B

    float* outp = (float*)d_out;
    float* kp_out = outp + (size_t)2 * 128 * HWs;         // outputs are f32 (ref dtype)

    k_prep<<<(NW_BF16 + 176 + 255) / 256, 256, 0, stream>>>(
        vc_w, vg_w, wc_w, wg_w, kpc_w, kpg_w, out_w,
        wc_b, wg_b, kpc_b, kpg_b, wbuf, bias176);
    k_stage1<<<2400, 256, 0, stream>>>(match, context, geometric,
                                       ln_g, ln_b, lnc_g, lnc_b, lng_g, lng_b,
                                       vc_b, vg_b, wbuf, bias176,
                                       anc_c, anc_g,
                                       ctx8, geo8, wts_g, coords_g, kp_out);
    k_agg<<<3200, 256, 0, stream>>>(ctx8, geo8, wts_g, coords_g, mask, aggf);
    k_out<<<800, 256, 0, stream>>>(aggf, wbuf + OFF_OUTB, out_b, outp);
}

// Round 12
// 205.708 us; speedup vs baseline: 1.0024x; 1.0024x over previous
//
#include <hip/hip_runtime.h>
#include <hip/hip_bf16.h>

typedef __hip_bfloat16 bf16;
typedef __bf16 b16x8 __attribute__((ext_vector_type(8)));
typedef float f32x4 __attribute__((ext_vector_type(4)));
typedef float f32x2 __attribute__((ext_vector_type(2)));

#define HWs   12800   // 80*160
#define NPIX  25600   // 2*80*160
#define IMG_H 80
#define IMG_W 160

// bf16 weight-cache element offsets inside wbuf
#define OFF_VCB  0        // 128x128
#define OFF_VGB  16384    // 128x128
#define OFF_MATB 32768    // 162x128  (wc|wg|kpc|kpg concatenated; reads up to row 175 spill into OUTB, stores guarded)
#define OFF_OUTB 53504    // 128x256
#define NW_BF16  86272

// fp8 e4m3 (OCP, gfx950-native) encode one float -> byte
static __device__ inline unsigned char enc_fp8(float v)
{
    return (unsigned char)(__builtin_amdgcn_cvt_pk_fp8_f32(v, v, 0, false) & 0xFF);
}

// ---------------- k_prep: f32 -> bf16 weight cache + concatenated bias ----------------
__global__ __launch_bounds__(256) void k_prep(
    const float* __restrict__ vc_w, const float* __restrict__ vg_w,
    const float* __restrict__ wc_w, const float* __restrict__ wg_w,
    const float* __restrict__ kpc_w, const float* __restrict__ kpg_w,
    const float* __restrict__ out_w,
    const float* __restrict__ wc_b, const float* __restrict__ wg_b,
    const float* __restrict__ kpc_b, const float* __restrict__ kpg_b,
    bf16* __restrict__ wbuf, float* __restrict__ bias176)
{
    int i = blockIdx.x * 256 + threadIdx.x;
    if (i < 16384) {
        wbuf[i] = __float2bfloat16(vc_w[i]);
    } else if (i < 32768) {
        wbuf[i] = __float2bfloat16(vg_w[i - 16384]);
    } else if (i < 53504) {
        int j = i - 32768; int row = j >> 7; int c = j & 127;
        float v;
        if (row < 72)       v = wc_w[row * 128 + c];
        else if (row < 144) v = wg_w[(row - 72) * 128 + c];
        else if (row < 153) v = kpc_w[(row - 144) * 128 + c];
        else                v = kpg_w[(row - 153) * 128 + c];
        wbuf[i] = __float2bfloat16(v);
    } else if (i < NW_BF16) {
        wbuf[i] = __float2bfloat16(out_w[i - 53504]);
    } else if (i < NW_BF16 + 176) {
        int j = i - NW_BF16;
        float v = 0.f;
        if (j < 72)       v = wc_b[j];
        else if (j < 144) v = wg_b[j - 72];
        else if (j < 153) v = kpc_b[j - 144];
        else if (j < 162) v = kpg_b[j - 153];
        bias176[j] = v;
    }
}

// ---------------- Stage 1: fused LN + GEMMs, weight prefetch overlap ----------------
// blocks [0,800): context+vc -> ctx8 (fp8) ; [800,1600): geometric+vg -> geo8 ;
// [1600,2400): match branch -> softmax wts, coords, kp_out.
// LN loads: direct per-thread scalar (half-wave-coalesced), proven best (R10 vs R11).
__global__ __launch_bounds__(256) void k_stage1(
    const float* __restrict__ match, const float* __restrict__ context, const float* __restrict__ geometric,
    const float* __restrict__ ln_g, const float* __restrict__ ln_b,
    const float* __restrict__ lnc_g, const float* __restrict__ lnc_b,
    const float* __restrict__ lng_g, const float* __restrict__ lng_b,
    const float* __restrict__ vc_b, const float* __restrict__ vg_b,
    const bf16* __restrict__ wbuf, const float* __restrict__ bias176,
    const float* __restrict__ anc_c, const float* __restrict__ anc_g,
    unsigned char* __restrict__ ctx8, unsigned char* __restrict__ geo8,
    bf16* __restrict__ wts_g, float* __restrict__ coords_g,
    float* __restrict__ kp_out)
{
    __shared__ __align__(16) bf16 tile_s[32 * 136];
    __shared__ bf16 logit_s[32 * 144];
    __shared__ float offs_s[32 * 18];
    __shared__ float red1[8][32];
    __shared__ float red2[8][32];

    int bx = blockIdx.x;
    int seg = bx / 800;                  // 0 ctx, 1 geo, 2 match
    int tile = bx - seg * 800;
    int t = threadIdx.x;
    int pixbase = tile * 32;

    const float* X  = (seg == 0) ? context : (seg == 1) ? geometric : match;
    const float* gg = (seg == 0) ? lnc_g   : (seg == 1) ? lng_g     : ln_g;
    const float* bb = (seg == 0) ? lnc_b   : (seg == 1) ? lng_b     : ln_b;

    // ---- issue LN global loads FIRST (oldest in vmcnt queue) ----
    int p = t & 31;
    int cq = t >> 5;
    int b = pixbase >= HWs;
    int hw0 = pixbase - b * HWs;
    const float* base = X + ((size_t)b * 128) * HWs + hw0 + p;
    float xv[16];
#pragma unroll
    for (int j = 0; j < 16; j++) xv[j] = base[(size_t)(cq * 16 + j) * HWs];

    // ---- prefetch this wave's B-fragments (independent of LN) ----
    int wv = t >> 6;
    int lane = t & 63;
    int s = wv >> 1;                     // subtile of 16 pixels
    int h = wv & 1;                      // output-tile parity
    int lrow = lane & 15;
    int lq = lane >> 4;
    const bf16* Wb = (seg == 0) ? wbuf + OFF_VCB
                   : (seg == 1) ? wbuf + OFF_VGB
                                : wbuf + OFF_MATB;
    b16x8 wf[4][4];
    float bpre[4];
#pragma unroll
    for (int i = 0; i < 4; i++) {
        int o = (h + 2 * i) * 16 + lrow;            // match: o <= 111 < 162, safe
        const bf16* wr = Wb + (size_t)o * 128;
#pragma unroll
        for (int kk = 0; kk < 4; kk++)
            wf[i][kk] = *(const b16x8*)(wr + (kk * 4 + lq) * 8);
        bpre[i] = (seg == 0) ? vc_b[o] : (seg == 1) ? vg_b[o] : bias176[o];
    }

    // ---- LN reduce + normalized bf16 tile ----
    {
        float s1 = 0.f, s2 = 0.f;
#pragma unroll
        for (int j = 0; j < 16; j++) { s1 += xv[j]; s2 += xv[j] * xv[j]; }
        red1[cq][p] = s1; red2[cq][p] = s2;
        __syncthreads();
        float S1 = 0.f, S2 = 0.f;
#pragma unroll
        for (int q = 0; q < 8; q++) { S1 += red1[q][p]; S2 += red2[q][p]; }
        float mean = S1 * (1.f / 128.f);
        float var  = fmaxf(S2 * (1.f / 128.f) - mean * mean, 0.f);
        float rstd = rsqrtf(var + 1e-5f);
#pragma unroll
        for (int j = 0; j < 16; j++) {
            int c = cq * 16 + j;
            float y = (xv[j] - mean) * rstd * gg[c] + bb[c];
            tile_s[p * 136 + c] = __float2bfloat16(y);
        }
        __syncthreads();
    }

    // ---- A fragments ----
    const b16x8* arow = (const b16x8*)(tile_s + (s * 16 + lrow) * 136);
    b16x8 af[4];
#pragma unroll
    for (int kk = 0; kk < 4; kk++) af[kk] = arow[kk * 4 + lq];

    if (seg < 2) {
        unsigned char* val = (seg == 0) ? ctx8 : geo8;
#pragma unroll
        for (int i = 0; i < 4; i++) {
            int o = (h + 2 * i) * 16 + lrow;
            f32x4 acc = {0.f, 0.f, 0.f, 0.f};
#pragma unroll
            for (int kk = 0; kk < 4; kk++)
                acc = __builtin_amdgcn_mfma_f32_16x16x32_bf16(af[kk], wf[i][kk], acc, 0, 0, 0);
#pragma unroll
            for (int r = 0; r < 4; r++) {
                int pix = pixbase + s * 16 + lq * 4 + r;   // C/D: row = lq*4+r, col = lrow
                val[(size_t)pix * 128 + o] = enc_fp8(acc[r] + bpre[i]);
            }
        }
        return;
    }

    // ---- seg == 2: match branch ----
#pragma unroll
    for (int i = 0; i < 4; i++) {
        int o = (h + 2 * i) * 16 + lrow;
        f32x4 acc = {0.f, 0.f, 0.f, 0.f};
#pragma unroll
        for (int kk = 0; kk < 4; kk++)
            acc = __builtin_amdgcn_mfma_f32_16x16x32_bf16(af[kk], wf[i][kk], acc, 0, 0, 0);
#pragma unroll
        for (int r = 0; r < 4; r++) {
            int row = s * 16 + lq * 4 + r;
            logit_s[row * 144 + o] = __float2bfloat16(acc[r] + bpre[i]);
        }
    }
    for (int ot = h + 8; ot < 11; ot += 2) {        // h=0: 8,10 ; h=1: 9
        int o = ot * 16 + lrow;                     // up to 175; reads padded, stores guarded
        const bf16* wr = Wb + (size_t)o * 128;
        f32x4 acc = {0.f, 0.f, 0.f, 0.f};
#pragma unroll
        for (int kk = 0; kk < 4; kk++)
            acc = __builtin_amdgcn_mfma_f32_16x16x32_bf16(af[kk], *(const b16x8*)(wr + (kk * 4 + lq) * 8), acc, 0, 0, 0);
        float bias = bias176[o];
#pragma unroll
        for (int r = 0; r < 4; r++) {
            int row = s * 16 + lq * 4 + r;
            float v = acc[r] + bias;
            if (o < 144)       logit_s[row * 144 + o] = __float2bfloat16(v);
            else if (o < 162)  offs_s[row * 18 + (o - 144)] = v;
        }
    }
    __syncthreads();

    // softmax over P per (pixel, branch, group): 512 tasks
#pragma unroll
    for (int i = 0; i < 2; i++) {
        int task = t + 256 * i;
        int lp = task >> 4;
        int sub = task & 15;
        int br = sub >> 3;
        int g = sub & 7;
        const bf16* basel = logit_s + lp * 144 + br * 72 + g;   // channel c = p*8+g
        float v[9];
        float m = -1e30f;
#pragma unroll
        for (int pp = 0; pp < 9; pp++) { v[pp] = __bfloat162float(basel[pp * 8]); m = fmaxf(m, v[pp]); }
        float ssum = 0.f;
#pragma unroll
        for (int pp = 0; pp < 9; pp++) { v[pp] = __expf(v[pp] - m); ssum += v[pp]; }
        float inv = 1.f / ssum;
        int pix = pixbase + lp;
        bf16* wbp = wts_g + ((size_t)pix * 2 + br) * 72 + g * 9;
#pragma unroll
        for (int pp = 0; pp < 9; pp++) wbp[pp] = __float2bfloat16(v[pp] * inv);
    }

    // keypoints + sample coords: 576 tasks (kp_out f32 = ref output dtype)
    for (int i = 0; i < 3; i++) {
        int task = t + 256 * i;
        if (task < 576) {
            int lp = task / 18;
            int sub = task - lp * 18;
            int br = sub / 9;
            int pp = sub - br * 9;
            int pix = pixbase + lp;
            float off = offs_s[lp * 18 + br * 9 + pp];
            const float* anc = br ? anc_g : anc_c;
            float ax = anc[(size_t)pix * 18 + pp * 2];
            float ay = anc[(size_t)pix * 18 + pp * 2 + 1];
            float kx = ax + off;
            float* kpo = kp_out + (size_t)br * (NPIX * 18) + (size_t)pix * 18 + pp * 2;
            kpo[0] = kx;
            kpo[1] = ay;
            float* cbp = coords_g + ((size_t)pix * 2 + br) * 18 + pp * 2;
            cbp[0] = kx * 160.f - 0.5f;
            cbp[1] = ay * 80.f - 0.5f;
        }
    }
}

// ---------------- bilinear gather (fp8) + aggregate, XCD-partitioned, packed math ----------------
// Quarter-wave (16 lanes) per (pixel,branch) task; lane owns 8 channels (8 B fp8).
// blockIdx&7 ~ XCD (round-robin dispatch): XCDs 0-3 -> ctx, 4-7 -> geo.
__global__ __launch_bounds__(256) void k_agg(
    const unsigned char* __restrict__ ctx8, const unsigned char* __restrict__ geo8,
    const bf16* __restrict__ wts_g, const float* __restrict__ coords_g,
    const float* __restrict__ mask,
    bf16* __restrict__ aggf)
{
    int t = threadIdx.x;
    int wv = t >> 6;
    int lane = t & 63;
    int q = lane >> 4;           // quarter-wave task slot
    int sub = lane & 15;         // channel octet
    int c0 = sub * 8;
    int g = sub >> 1;            // group = c/16

    int bx = blockIdx.x;         // 0..3199
    int xcd = bx & 7;
    int br = xcd >> 2;           // XCDs 0-3 -> ctx, 4-7 -> geo
    int grp = (bx >> 3) * 4 + (xcd & 3);      // 0..1599
    int pix = grp * 16 + wv * 4 + q;          // 0..25599
    int tk = pix * 2 + br;
    int b = pix >= HWs;
    int rowbase = b * HWs;

    const unsigned char* val = br ? geo8 : ctx8;
    const float* cb = coords_g + (size_t)tk * 18;
    const bf16* wb = wts_g + (size_t)tk * 72 + g * 9;

    float wtv[9];
#pragma unroll
    for (int pp = 0; pp < 9; pp++) wtv[pp] = __bfloat162float(wb[pp]);

    f32x2 acc2[4] = {{0.f, 0.f}, {0.f, 0.f}, {0.f, 0.f}, {0.f, 0.f}};
    for (int pp = 0; pp < 9; pp++) {
        float px = cb[pp * 2];
        float py = cb[pp * 2 + 1];
        float fx = floorf(px), fy = floorf(py);
        float dx = px - fx, dy = py - fy;
        int x0 = (int)fx, y0 = (int)fy;
        float wt = wtv[pp];
#pragma unroll
        for (int c4 = 0; c4 < 4; c4++) {
            int xi = x0 + (c4 & 1);
            int yi = y0 + (c4 >> 1);
            bool ok = (xi >= 0) & (xi < IMG_W) & (yi >= 0) & (yi < IMG_H);
            int xc = min(max(xi, 0), IMG_W - 1);
            int yc = min(max(yi, 0), IMG_H - 1);
            float wx = (c4 & 1) ? dx : 1.f - dx;
            float wy = (c4 >> 1) ? dy : 1.f - dy;
            float wgt = ok ? wx * wy * wt : 0.f;
            f32x2 w2 = {wgt, wgt};
            uint2 u = *(const uint2*)(val + (size_t)(rowbase + yc * IMG_W + xc) * 128 + c0);
            acc2[0] += w2 * __builtin_amdgcn_cvt_pk_f32_fp8(u.x, false);
            acc2[1] += w2 * __builtin_amdgcn_cvt_pk_f32_fp8(u.x, true);
            acc2[2] += w2 * __builtin_amdgcn_cvt_pk_f32_fp8(u.y, false);
            acc2[3] += w2 * __builtin_amdgcn_cvt_pk_f32_fp8(u.y, true);
        }
    }
    float mv = (br == 0) ? mask[pix] : 1.f;
    b16x8 pk;
#pragma unroll
    for (int j = 0; j < 8; j++) pk[j] = (__bf16)(acc2[j >> 1][j & 1] * mv);
    *(b16x8*)(aggf + (size_t)pix * 256 + br * 128 + c0) = pk;
}

// ---------------- final projection (MFMA, K=256) + LDS-staged coalesced f32 store ----------------
__global__ __launch_bounds__(256) void k_out(
    const bf16* __restrict__ aggf,
    const bf16* __restrict__ outb, const float* __restrict__ out_b,
    float* __restrict__ out)
{
    __shared__ float ot_s[128 * 33];     // pitch 33: (row+col) bank map -> 2-way (free)
    int t = threadIdx.x;
    int pixbase = blockIdx.x * 32;       // 800 blocks
    int wv = t >> 6;
    int lane = t & 63;
    int s = wv >> 1;
    int h = wv & 1;
    int lrow = lane & 15;
    int lq = lane >> 4;
    const b16x8* arow = (const b16x8*)(aggf + (size_t)(pixbase + s * 16 + lrow) * 256);
    b16x8 af[8];
#pragma unroll
    for (int kk = 0; kk < 8; kk++) af[kk] = arow[kk * 4 + lq];
    int b = pixbase >= HWs;
#pragma unroll
    for (int i = 0; i < 4; i++) {
        int o = (h + 2 * i) * 16 + lrow;
        const bf16* wrow = outb + (size_t)o * 256;
        f32x4 acc = {0.f, 0.f, 0.f, 0.f};
#pragma unroll
        for (int kk = 0; kk < 8; kk++)
            acc = __builtin_amdgcn_mfma_f32_16x16x32_bf16(af[kk], *(const b16x8*)(wrow + (kk * 4 + lq) * 8), acc, 0, 0, 0);
        float bias = out_b[o];
#pragma unroll
        for (int r = 0; r < 4; r++)
            ot_s[o * 33 + (s * 16 + lq * 4 + r)] = acc[r] + bias;
    }
    __syncthreads();

    // coalesced writeout: thread pair per channel row; 128 B contiguous per pair
    int row = t >> 1;                    // channel 0..127
    int ch0 = (t & 1) * 16;              // half-row
    int hwb = pixbase - b * HWs;
    float* orow = out + (size_t)b * (128 * HWs) + (size_t)row * HWs + hwb + ch0;
    const float* srow = ot_s + row * 33 + ch0;
#pragma unroll
    for (int j = 0; j < 4; j++) {
        float4 v = {srow[4 * j], srow[4 * j + 1], srow[4 * j + 2], srow[4 * j + 3]};
        *(float4*)(orow + 4 * j) = v;
    }
}

extern "C" void kernel_launch(void* const* d_in, const int* in_sizes, int n_in,
                              void* d_out, int out_size, void* d_ws, size_t ws_size,
                              hipStream_t stream)
{
    const float* mask      = (const float*)d_in[0];
    const float* match     = (const float*)d_in[1];
    const float* context   = (const float*)d_in[2];
    const float* geometric = (const float*)d_in[3];
    const float* anc_c     = (const float*)d_in[4];
    const float* anc_g     = (const float*)d_in[5];
    const float* ln_g  = (const float*)d_in[6];
    const float* ln_b  = (const float*)d_in[7];
    const float* lnc_g = (const float*)d_in[8];
    const float* lnc_b = (const float*)d_in[9];
    const float* lng_g = (const float*)d_in[10];
    const float* lng_b = (const float*)d_in[11];
    const float* wc_w  = (const float*)d_in[12];
    const float* wc_b  = (const float*)d_in[13];
    const float* wg_w  = (const float*)d_in[14];
    const float* wg_b  = (const float*)d_in[15];
    const float* vc_w  = (const float*)d_in[16];
    const float* vc_b  = (const float*)d_in[17];
    const float* vg_w  = (const float*)d_in[18];
    const float* vg_b  = (const float*)d_in[19];
    const float* out_w = (const float*)d_in[20];
    const float* out_b = (const float*)d_in[21];
    const float* kpc_w = (const float*)d_in[22];
    const float* kpc_b = (const float*)d_in[23];
    const float* kpg_w = (const float*)d_in[24];
    const float* kpg_b = (const float*)d_in[25];

    // d_ws layout
    char* w = (char*)d_ws;
    unsigned char* ctx8 = (unsigned char*)(w);            //  3,276,800 B (fp8)
    unsigned char* geo8 = (unsigned char*)(w + 3276800);  //  3,276,800 B
    bf16*  wts_g    = (bf16*)(w + 6553600);               //  7,372,800 B
    float* coords_g = (float*)(w + 13926400);             //  3,686,400 B
    bf16*  aggf     = (bf16*)(w + 17612800);              // 13,107,200 B
    bf16*  wbuf     = (bf16*)(w + 30720000);              //    172,544 B
    float* bias176  = (float*)(w + 30892544);             //        704 B

    float* outp = (float*)d_out;
    float* kp_out = outp + (size_t)2 * 128 * HWs;         // outputs are f32 (ref dtype)

    k_prep<<<(NW_BF16 + 176 + 255) / 256, 256, 0, stream>>>(
        vc_w, vg_w, wc_w, wg_w, kpc_w, kpg_w, out_w,
        wc_b, wg_b, kpc_b, kpg_b, wbuf, bias176);
    k_stage1<<<2400, 256, 0, stream>>>(match, context, geometric,
                                       ln_g, ln_b, lnc_g, lnc_b, lng_g, lng_b,
                                       vc_b, vg_b, wbuf, bias176,
                                       anc_c, anc_g,
                                       ctx8, geo8, wts_g, coords_g, kp_out);
    k_agg<<<3200, 256, 0, stream>>>(ctx8, geo8, wts_g, coords_g, mask, aggf);
    k_out<<<800, 256, 0, stream>>>(aggf, wbuf + OFF_OUTB, out_b, outp);
}